// Round 12
// baseline (112.086 us; speedup 1.0000x reference)
//
#include <hip/hip_runtime.h>
#include <hip/hip_bf16.h>

#define NPIX 65536
#define NRAYS 65536
#define SS 48
#define NC 256
#define ND 16

typedef __attribute__((ext_vector_type(8))) short short8;
typedef __attribute__((ext_vector_type(4))) float f32x4;

__device__ __forceinline__ unsigned short f2bf(float x) {
    unsigned u = __float_as_uint(x);
    unsigned r = u + 0x7fff + ((u >> 16) & 1);
    return (unsigned short)(r >> 16);
}
__device__ __forceinline__ float bf2f(unsigned short h) {
    return __uint_as_float(((unsigned)h) << 16);
}

// ---------------- kA: pixel pass (rgb, opac, class count/sum, norm partials) ----------------
__global__ __launch_bounds__(256) void kA(
    const float* __restrict__ rgb_pred, const float* __restrict__ rgb_gt,
    const float* __restrict__ opacity, const int* __restrict__ sam,
    const float* __restrict__ semantic,
    float* __restrict__ o_rgb, float* __restrict__ o_opac,
    float* __restrict__ cntpart, float* __restrict__ usumpart,
    float* __restrict__ normpart, float* __restrict__ wsumpart, int ppbA)
{
    __shared__ float cnt_s[NC];
    __shared__ float us_s[NC*17];
    __shared__ float red_s[8];
    const int t = threadIdx.x;
    const int b = blockIdx.x;
    for (int j = t; j < NC; j += 256) cnt_s[j] = 0.f;
    for (int j = t; j < NC*17; j += 256) us_s[j] = 0.f;
    __syncthreads();
    float nloc = 0.f, wloc = 0.f;
    for (int p = 0; p < ppbA; ++p) {
        const int i = (b*ppbA + p)*256 + t;
        const float pr0 = rgb_pred[3*i+0], pr1 = rgb_pred[3*i+1], pr2 = rgb_pred[3*i+2];
        const float g0 = rgb_gt[3*i+0],  g1 = rgb_gt[3*i+1],  g2 = rgb_gt[3*i+2];
        const float d0 = pr0-g0, d1 = pr1-g1, d2 = pr2-g2;
        o_rgb[3*i+0] = d0*d0; o_rgb[3*i+1] = d1*d1; o_rgb[3*i+2] = d2*d2;
        const float o = opacity[i] + 1e-10f;
        o_opac[i] = -0.001f * o * logf(o);
        const float4* sp = (const float4*)(semantic + (size_t)i*ND);
        const float4 a0 = sp[0], a1 = sp[1], a2 = sp[2], a3 = sp[3];
        const int seg = sam[i];
        if (seg > 0) {
            const int cl = seg - 1;
            const float ss =
                a0.x*a0.x + a0.y*a0.y + a0.z*a0.z + a0.w*a0.w +
                a1.x*a1.x + a1.y*a1.y + a1.z*a1.z + a1.w*a1.w +
                a2.x*a2.x + a2.y*a2.y + a2.z*a2.z + a2.w*a2.w +
                a3.x*a3.x + a3.y*a3.y + a3.z*a3.z + a3.w*a3.w;
            const float dn = sqrtf(ss) - 1.f;
            nloc += dn*dn; wloc += 1.f;
            atomicAdd(&cnt_s[cl], 1.f);
            float* up = us_s + cl*17;
            atomicAdd(up+0,  a0.x); atomicAdd(up+1,  a0.y);
            atomicAdd(up+2,  a0.z); atomicAdd(up+3,  a0.w);
            atomicAdd(up+4,  a1.x); atomicAdd(up+5,  a1.y);
            atomicAdd(up+6,  a1.z); atomicAdd(up+7,  a1.w);
            atomicAdd(up+8,  a2.x); atomicAdd(up+9,  a2.y);
            atomicAdd(up+10, a2.z); atomicAdd(up+11, a2.w);
            atomicAdd(up+12, a3.x); atomicAdd(up+13, a3.y);
            atomicAdd(up+14, a3.z); atomicAdd(up+15, a3.w);
        }
    }
    __syncthreads();
    for (int j = t; j < NC; j += 256) cntpart[b*NC + j] = cnt_s[j];
    for (int j = t; j < NC*ND; j += 256) {
        const int c = j >> 4, k = j & 15;
        usumpart[(size_t)b*NC*ND + j] = us_s[c*17 + k];
    }
    for (int off = 32; off > 0; off >>= 1) {
        nloc += __shfl_down(nloc, off);
        wloc += __shfl_down(wloc, off);
    }
    if ((t & 63) == 0) { red_s[t>>6] = nloc; red_s[4 + (t>>6)] = wloc; }
    __syncthreads();
    if (t == 0) {
        normpart[b] = red_s[0]+red_s[1]+red_s[2]+red_s[3];
        wsumpart[b] = red_s[4]+red_s[5]+red_s[6]+red_s[7];
    }
}

// ---------------- kP1: per-class block reduce -> cnt, u; block 0 also norm/wsum ----------------
__global__ __launch_bounds__(256) void kP1(
    const float* __restrict__ cntpart, const float* __restrict__ usumpart,
    const float* __restrict__ normpart, const float* __restrict__ wsumpart,
    float* __restrict__ cnt, float* __restrict__ u,
    float* __restrict__ scal, int nblkA)
{
    const int c = blockIdx.x;
    const int t = threadIdx.x;
    const int kk = t & 15;
    const int s  = t >> 4;

    float us = 0.f;
    for (int b = s; b < nblkA; b += 16)
        us += usumpart[(size_t)b*(NC*ND) + c*ND + kk];

    __shared__ float lds[16][17];
    lds[s][kk] = us;

    float cs = (t < nblkA) ? cntpart[t*NC + c] : 0.f;
#pragma unroll
    for (int off = 32; off > 0; off >>= 1) cs += __shfl_xor(cs, off);
    __shared__ float cred[4];
    if ((t & 63) == 0) cred[t >> 6] = cs;
    __syncthreads();

    if (t < 16) {
        const float ctot = cred[0]+cred[1]+cred[2]+cred[3];
        float tot = 0.f;
#pragma unroll
        for (int s2 = 0; s2 < 16; ++s2) tot += lds[s2][t];
        u[c*ND + t] = tot / fmaxf(ctot, 1.f);
        if (t == 0) cnt[c] = ctot;
    }

    if (c == 0) {
        float n = (t < nblkA) ? normpart[t] : 0.f;
        float w2 = (t < nblkA) ? wsumpart[t] : 0.f;
#pragma unroll
        for (int off = 32; off > 0; off >>= 1) {
            n  += __shfl_xor(n, off);
            w2 += __shfl_xor(w2, off);
        }
        __shared__ float nr[4], wr[4];
        if ((t & 63) == 0) { nr[t >> 6] = n; wr[t >> 6] = w2; }
        __syncthreads();
        if (t == 0) {
            scal[0] = nr[0]+nr[1]+nr[2]+nr[3];
            scal[1] = wr[0]+wr[1]+wr[2]+wr[3];
        }
    }
}

// ---------------- kC: per-class deviation partials ----------------
__global__ __launch_bounds__(256) void kC(
    const float* __restrict__ semantic, const int* __restrict__ sam,
    const float* __restrict__ u, float* __restrict__ devpart, int ppb)
{
    __shared__ float u_s[NC*20];
    __shared__ float dev_s[NC];
    const int t = threadIdx.x, b = blockIdx.x;
    for (int j = t; j < NC*ND; j += 256) {
        const int c = j >> 4, k = j & 15;
        u_s[c*20 + k] = u[j];
    }
    for (int j = t; j < NC; j += 256) dev_s[j] = 0.f;
    __syncthreads();
    for (int p = 0; p < ppb; ++p) {
        const int i = (b*ppb + p)*256 + t;
        const int seg = sam[i];
        if (seg > 0) {
            const int cl = seg - 1;
            const float4* sp = (const float4*)(semantic + (size_t)i*ND);
            const float4 a0 = sp[0], a1 = sp[1], a2 = sp[2], a3 = sp[3];
            const float4* up = (const float4*)(u_s + cl*20);
            const float4 u0 = up[0], u1 = up[1], u2 = up[2], u3 = up[3];
            float q, d2 = 0.f;
            q = a0.x-u0.x; d2 += q*q;  q = a0.y-u0.y; d2 += q*q;
            q = a0.z-u0.z; d2 += q*q;  q = a0.w-u0.w; d2 += q*q;
            q = a1.x-u1.x; d2 += q*q;  q = a1.y-u1.y; d2 += q*q;
            q = a1.z-u1.z; d2 += q*q;  q = a1.w-u1.w; d2 += q*q;
            q = a2.x-u2.x; d2 += q*q;  q = a2.y-u2.y; d2 += q*q;
            q = a2.z-u2.z; d2 += q*q;  q = a2.w-u2.w; d2 += q*q;
            q = a3.x-u3.x; d2 += q*q;  q = a3.y-u3.y; d2 += q*q;
            q = a3.z-u3.z; d2 += q*q;  q = a3.w-u3.w; d2 += q*q;
            atomicAdd(&dev_s[cl], sqrtf(d2));
        }
    }
    __syncthreads();
    for (int j = t; j < NC; j += 256) devpart[b*NC + j] = dev_s[j];
}

// ---------------- kP2: per-class phi -> uphi (f32 + bf16 hi), mask; zero scal[2]/done ----------------
__global__ __launch_bounds__(256) void kP2(
    const float* __restrict__ devpart, const float* __restrict__ cnt,
    const float* __restrict__ u, float* __restrict__ uphi,
    unsigned short* __restrict__ uphi_h,
    float* __restrict__ mf, float* __restrict__ scal, int nblkC)
{
    const int c = blockIdx.x;
    const int t = threadIdx.x;

    if (c == 0 && t == 0) {
        scal[2] = 0.f;
        ((unsigned*)scal)[3] = 0u;
    }

    float dv = (t < nblkC) ? devpart[t*NC + c] : 0.f;
#pragma unroll
    for (int off = 32; off > 0; off >>= 1) dv += __shfl_xor(dv, off);
    __shared__ float dred[4];
    __shared__ float inv_s;
    if ((t & 63) == 0) dred[t >> 6] = dv;
    __syncthreads();

    if (t == 0) {
        const float dtot = dred[0]+dred[1]+dred[2]+dred[3];
        const float cs = cnt[c];
        const float csafe = fmaxf(cs, 1.f);
        const float phiraw = dtot / (csafe * logf(cs + 10.f));
        const float phi = fminf(fmaxf(phiraw * 10.f, 0.1f), 1.f);
        inv_s = 1.f / phi;
        mf[c] = (cs > 2.0f) ? 1.f : 0.f;
    }
    __syncthreads();
    if (t < 16) {
        const float v = u[c*ND + t] * inv_s;
        uphi[c*ND + t] = v;
        uphi_h[c*ND + t] = f2bf(v);
    }
}

// ---------------- kFuse: blocks [0,ndblk) = NCE via MFMA; rest = distortion ----------------
// kD part: 1024 blocks x 4 waves; wave = one 16-pixel tile x all 256 classes.
// A = [sem_hi | sem_lo] (K=32), B = [u_hi | u_hi]: mfma gives hi*hi + lo*hi
// (hi*lo dropped: <= 2^-9 relative on logits, ~20x under tolerance).
// kDist part: wave-per-ray shuffle prefix scan (no LDS).
__global__ __launch_bounds__(256) void kFuse(
    const float* __restrict__ semantic, const int* __restrict__ sam,
    const float* __restrict__ uphi, const unsigned short* __restrict__ uphi_h,
    const float* __restrict__ mf,
    float* __restrict__ scal, float* __restrict__ o_sem,
    const float* __restrict__ wsv, const float* __restrict__ deltas,
    const float* __restrict__ tsv, const int* __restrict__ rays_a,
    float* __restrict__ o_dist, int ndblk)
{
    const int t = threadIdx.x;
    const int lane = t & 63;
    const int w = t >> 6;

    if ((int)blockIdx.x < ndblk) {
        // ---------------- NCE ----------------
        __shared__ float dlds[4][16];
        __shared__ float red_s[4];
        const int col = lane & 15;          // pixel within tile (A-row / D-col... see layout note)
        const int g   = lane >> 4;          // k-octet group
        const int wbase = blockIdx.x*64 + w*16;

        // A fragment: lane holds dims (g&1)*8..+7 of pixel `col`; hi if g<2 else lo
        short8 A;
        {
            const float* sp = semantic + (size_t)(wbase + col)*ND + (g & 1)*8;
            const float4 f0 = ((const float4*)sp)[0];
            const float4 f1 = ((const float4*)sp)[1];
            float fv[8] = {f0.x,f0.y,f0.z,f0.w, f1.x,f1.y,f1.z,f1.w};
#pragma unroll
            for (int i = 0; i < 8; ++i) {
                const unsigned short h = f2bf(fv[i]);
                const unsigned short l = f2bf(fv[i] - bf2f(h));
                A[i] = (short)((g < 2) ? h : l);
            }
        }

        // B fragments: 16 class-tiles, hi only ([hi|hi] along K=32)
        short8 B1[16];
        const short8* Bh = (const short8*)uphi_h;
#pragma unroll
        for (int ct = 0; ct < 16; ++ct)
            B1[ct] = Bh[(ct*16 + col)*2 + (g & 1)];

        float mfv[16];
#pragma unroll
        for (int ct = 0; ct < 16; ++ct) mfv[ct] = mf[ct*16 + col];

        float dacc[4] = {0.f, 0.f, 0.f, 0.f};
#pragma unroll
        for (int ct = 0; ct < 16; ++ct) {
            f32x4 d = {0.f, 0.f, 0.f, 0.f};
            d = __builtin_amdgcn_mfma_f32_16x16x32_bf16(A, B1[ct], d, 0, 0, 0);
#pragma unroll
            for (int r = 0; r < 4; ++r)
                dacc[r] += mfv[ct] * __expf(d[r]);
        }

        // sum over class-columns (lanes sharing g): xor 1,2,4,8
#pragma unroll
        for (int r = 0; r < 4; ++r) {
            float v = dacc[r];
            v += __shfl_xor(v, 1);
            v += __shfl_xor(v, 2);
            v += __shfl_xor(v, 4);
            v += __shfl_xor(v, 8);
            dacc[r] = v;
        }
        if (col == 0) {
#pragma unroll
            for (int r = 0; r < 4; ++r)
                dlds[w][4*g + r] = dacc[r];   // pixel wbase + 4g + r
        }
        __syncthreads();

        float contrib = 0.f;
        if (t < 64) {
            const int p = blockIdx.x*64 + t;
            const float denom = dlds[t >> 4][t & 15] + 1e-6f;
            const int seg = sam[p];
            const int cl = (seg > 0) ? (seg - 1) : 0;
            const float4* sp = (const float4*)(semantic + (size_t)p*ND);
            const float4 b0 = sp[0], b1 = sp[1], b2 = sp[2], b3 = sp[3];
            const float4* uo = (const float4*)(uphi + cl*ND);
            const float4 c0 = uo[0], c1 = uo[1], c2 = uo[2], c3 = uo[3];
            const float down =
                b0.x*c0.x + b0.y*c0.y + b0.z*c0.z + b0.w*c0.w +
                b1.x*c1.x + b1.y*c1.y + b1.z*c1.z + b1.w*c1.w +
                b2.x*c2.x + b2.y*c2.y + b2.z*c2.z + b2.w*c2.w +
                b3.x*c3.x + b3.y*c3.y + b3.z*c3.z + b3.w*c3.w;
            const float mo = mf[cl];
            contrib = (seg > 0 && mo > 0.5f) ? (__logf(denom) - down) : 0.f;
        }
#pragma unroll
        for (int off = 32; off > 0; off >>= 1) contrib += __shfl_xor(contrib, off);
        if ((t & 63) == 0) red_s[t >> 6] = contrib;
        __syncthreads();
        if (t == 0) {
            atomicAdd(&scal[2], red_s[0]+red_s[1]+red_s[2]+red_s[3]);
            __threadfence();
            unsigned* done = (unsigned*)(scal + 3);
            const unsigned old = atomicAdd(done, 1u);
            if (old == (unsigned)(ndblk - 1)) {
                const float proto = atomicAdd(&scal[2], 0.f);
                o_sem[0] = 1e-4f * proto + 100.f * scal[0] / fmaxf(scal[1], 1.f);
            }
        }
    } else {
        // ---------------- distortion: one wave per ray ----------------
        const int bD = blockIdx.x - ndblk;
        const int ray = bD*4 + w;
        const int start = rays_a[3*ray + 1];
        const int cnt   = rays_a[3*ray + 2];
        const bool act = lane < cnt;
        const float w_ = act ? wsv[start+lane]    : 0.f;
        const float t_ = act ? tsv[start+lane]    : 0.f;
        const float d_ = act ? deltas[start+lane] : 0.f;
        const float wt_ = w_*t_;
        float sw = w_, swt = wt_;
#pragma unroll
        for (int off = 1; off < 64; off <<= 1) {
            const float aw  = __shfl_up(sw, off);
            const float awt = __shfl_up(swt, off);
            if (lane >= off) { sw += aw; swt += awt; }
        }
        const float Wex = sw - w_, WTex = swt - wt_;
        float per = 2.f*w_*(t_*Wex - WTex) + w_*w_*d_*(1.f/3.f);
#pragma unroll
        for (int off = 32; off > 0; off >>= 1) per += __shfl_xor(per, off);
        if (lane == 0) o_dist[ray] = 0.001f * per;
    }
}

extern "C" void kernel_launch(void* const* d_in, const int* in_sizes, int n_in,
                              void* d_out, int out_size, void* d_ws, size_t ws_size,
                              hipStream_t stream)
{
    const float* rgb_pred = (const float*)d_in[0];
    const float* rgb_gt   = (const float*)d_in[1];
    const float* opacity  = (const float*)d_in[2];
    const float* wsv      = (const float*)d_in[3];
    const float* deltas   = (const float*)d_in[4];
    const float* tsv      = (const float*)d_in[5];
    const int*   rays_a   = (const int*)d_in[6];
    const int*   sam      = (const int*)d_in[7];
    const float* semantic = (const float*)d_in[8];

    float* out    = (float*)d_out;
    float* o_rgb  = out;                 // 196608
    float* o_opac = out + 196608;        // 65536
    float* o_dist = out + 262144;        // 65536
    float* o_sem  = out + 327680;        // 1
    float* wsf    = (float*)d_ws;

    int nblkA = 256, nblkC = 256;
    size_t need = ((size_t)nblkA*NC*(ND+1) + (size_t)nblkC*NC + NC + 2*NC*ND + 2*nblkA + 64) * 4;
    if (ws_size < need) { nblkA = 128; nblkC = 128; }
    const int ppbA = NPIX / (nblkA * 256);
    const int ppbC = NPIX / (nblkC * 256);

    float*          w_cntpart  = wsf;
    float*          w_usum     = w_cntpart + (size_t)nblkA*NC;
    float*          w_devpart  = w_usum + (size_t)nblkA*NC*ND;
    float*          w_cnt      = w_devpart + (size_t)nblkC*NC;
    float*          w_u        = w_cnt + NC;
    float*          w_uphi     = w_u + NC*ND;
    float*          w_scal     = w_uphi + NC*ND;          // [0]=norm [1]=wsum [2]=proto [3]=done
    float*          w_mf       = w_scal + 8;              // NC floats
    float*          w_normpart = w_mf + NC;               // nblkA floats
    float*          w_wsumpart = w_normpart + nblkA;      // nblkA floats
    unsigned short* w_uh       = (unsigned short*)(w_wsumpart + nblkA);  // NC*ND bf16 hi

    const int ndblk = NPIX / 64;        // 1024 NCE blocks
    const int ndistblk = NRAYS / 4;     // 16384 distortion blocks (wave-per-ray)

    kA<<<nblkA, 256, 0, stream>>>(rgb_pred, rgb_gt, opacity, sam, semantic,
                                  o_rgb, o_opac, w_cntpart, w_usum,
                                  w_normpart, w_wsumpart, ppbA);
    kP1<<<NC, 256, 0, stream>>>(w_cntpart, w_usum, w_normpart, w_wsumpart,
                                w_cnt, w_u, w_scal, nblkA);
    kC<<<nblkC, 256, 0, stream>>>(semantic, sam, w_u, w_devpart, ppbC);
    kP2<<<NC, 256, 0, stream>>>(w_devpart, w_cnt, w_u, w_uphi, w_uh,
                                w_mf, w_scal, nblkC);
    kFuse<<<ndblk + ndistblk, 256, 0, stream>>>(semantic, sam, w_uphi, w_uh, w_mf,
                                                w_scal, o_sem,
                                                wsv, deltas, tsv, rays_a, o_dist, ndblk);
}

// Round 13
// 70.565 us; speedup vs baseline: 1.5884x; 1.5884x over previous
//
#include <hip/hip_runtime.h>
#include <hip/hip_bf16.h>

#define NPIX 65536
#define NRAYS 65536
#define SS 48
#define NC 256
#define ND 16
#define RPB 128   // rays per kDist block (128 threads)

typedef __attribute__((ext_vector_type(8))) short short8;
typedef __attribute__((ext_vector_type(4))) float f32x4;

__device__ __forceinline__ unsigned short f2bf(float x) {
    unsigned u = __float_as_uint(x);
    unsigned r = u + 0x7fff + ((u >> 16) & 1);
    return (unsigned short)(r >> 16);
}
__device__ __forceinline__ float bf2f(unsigned short h) {
    return __uint_as_float(((unsigned)h) << 16);
}

// ---------------- kA: pixel pass (rgb, opac, class count/sum, norm partials) ----------------
__global__ __launch_bounds__(256) void kA(
    const float* __restrict__ rgb_pred, const float* __restrict__ rgb_gt,
    const float* __restrict__ opacity, const int* __restrict__ sam,
    const float* __restrict__ semantic,
    float* __restrict__ o_rgb, float* __restrict__ o_opac,
    float* __restrict__ cntpart, float* __restrict__ usumpart,
    float* __restrict__ normpart, float* __restrict__ wsumpart, int ppbA)
{
    __shared__ float cnt_s[NC];
    __shared__ float us_s[NC*17];
    __shared__ float red_s[8];
    const int t = threadIdx.x;
    const int b = blockIdx.x;
    for (int j = t; j < NC; j += 256) cnt_s[j] = 0.f;
    for (int j = t; j < NC*17; j += 256) us_s[j] = 0.f;
    __syncthreads();
    float nloc = 0.f, wloc = 0.f;
    for (int p = 0; p < ppbA; ++p) {
        const int i = (b*ppbA + p)*256 + t;
        const float pr0 = rgb_pred[3*i+0], pr1 = rgb_pred[3*i+1], pr2 = rgb_pred[3*i+2];
        const float g0 = rgb_gt[3*i+0],  g1 = rgb_gt[3*i+1],  g2 = rgb_gt[3*i+2];
        const float d0 = pr0-g0, d1 = pr1-g1, d2 = pr2-g2;
        o_rgb[3*i+0] = d0*d0; o_rgb[3*i+1] = d1*d1; o_rgb[3*i+2] = d2*d2;
        const float o = opacity[i] + 1e-10f;
        o_opac[i] = -0.001f * o * logf(o);
        const float4* sp = (const float4*)(semantic + (size_t)i*ND);
        const float4 a0 = sp[0], a1 = sp[1], a2 = sp[2], a3 = sp[3];
        const int seg = sam[i];
        if (seg > 0) {
            const int cl = seg - 1;
            const float ss =
                a0.x*a0.x + a0.y*a0.y + a0.z*a0.z + a0.w*a0.w +
                a1.x*a1.x + a1.y*a1.y + a1.z*a1.z + a1.w*a1.w +
                a2.x*a2.x + a2.y*a2.y + a2.z*a2.z + a2.w*a2.w +
                a3.x*a3.x + a3.y*a3.y + a3.z*a3.z + a3.w*a3.w;
            const float dn = sqrtf(ss) - 1.f;
            nloc += dn*dn; wloc += 1.f;
            atomicAdd(&cnt_s[cl], 1.f);
            float* up = us_s + cl*17;
            atomicAdd(up+0,  a0.x); atomicAdd(up+1,  a0.y);
            atomicAdd(up+2,  a0.z); atomicAdd(up+3,  a0.w);
            atomicAdd(up+4,  a1.x); atomicAdd(up+5,  a1.y);
            atomicAdd(up+6,  a1.z); atomicAdd(up+7,  a1.w);
            atomicAdd(up+8,  a2.x); atomicAdd(up+9,  a2.y);
            atomicAdd(up+10, a2.z); atomicAdd(up+11, a2.w);
            atomicAdd(up+12, a3.x); atomicAdd(up+13, a3.y);
            atomicAdd(up+14, a3.z); atomicAdd(up+15, a3.w);
        }
    }
    __syncthreads();
    for (int j = t; j < NC; j += 256) cntpart[b*NC + j] = cnt_s[j];
    for (int j = t; j < NC*ND; j += 256) {
        const int c = j >> 4, k = j & 15;
        usumpart[(size_t)b*NC*ND + j] = us_s[c*17 + k];
    }
    for (int off = 32; off > 0; off >>= 1) {
        nloc += __shfl_down(nloc, off);
        wloc += __shfl_down(wloc, off);
    }
    if ((t & 63) == 0) { red_s[t>>6] = nloc; red_s[4 + (t>>6)] = wloc; }
    __syncthreads();
    if (t == 0) {
        normpart[b] = red_s[0]+red_s[1]+red_s[2]+red_s[3];
        wsumpart[b] = red_s[4]+red_s[5]+red_s[6]+red_s[7];
    }
}

// ---------------- kDist: LDS-transposed serial scan, 1 thread/ray ----------------
__global__ __launch_bounds__(128) void kDist(
    const float* __restrict__ wsv, const float* __restrict__ deltas,
    const float* __restrict__ tsv, const int* __restrict__ rays_a,
    float* __restrict__ o_dist)
{
    __shared__ float wS[SS][RPB+1];
    __shared__ float tS[SS][RPB+1];
    __shared__ float dS[SS][RPB+1];
    __shared__ int bad;
    const int t = threadIdx.x;
    const int r0 = blockIdx.x * RPB;
    const int ray = r0 + t;
    if (t == 0) bad = 0;
    __syncthreads();
    const int start = rays_a[3*ray + 1];
    const int cnt   = rays_a[3*ray + 2];
    if (start != ray*SS || cnt != SS) atomicAdd(&bad, 1);
    __syncthreads();

    if (bad == 0) {
        const size_t gb = (size_t)r0 * SS;
        const float4* gw = (const float4*)(wsv + gb);
        const float4* gt = (const float4*)(tsv + gb);
        const float4* gd = (const float4*)(deltas + gb);
        for (int i = t; i < RPB*SS/4; i += 128) {
            const int e = i*4;
            const int rr = e / SS;
            const int jj = e % SS;
            const float4 a = gw[i], b = gt[i], c = gd[i];
            wS[jj+0][rr]=a.x; wS[jj+1][rr]=a.y; wS[jj+2][rr]=a.z; wS[jj+3][rr]=a.w;
            tS[jj+0][rr]=b.x; tS[jj+1][rr]=b.y; tS[jj+2][rr]=b.z; tS[jj+3][rr]=b.w;
            dS[jj+0][rr]=c.x; dS[jj+1][rr]=c.y; dS[jj+2][rr]=c.z; dS[jj+3][rr]=c.w;
        }
        __syncthreads();
        float W = 0.f, WT = 0.f, acc = 0.f;
        for (int j = 0; j < SS; ++j) {
            const float w_ = wS[j][t], t_ = tS[j][t], d_ = dS[j][t];
            acc += 2.f*w_*(t_*W - WT) + w_*w_*d_*(1.f/3.f);
            W += w_; WT += w_*t_;
        }
        o_dist[ray] = 0.001f * acc;
    } else {
        float W = 0.f, WT = 0.f, acc = 0.f;
        for (int j = 0; j < cnt; ++j) {
            const float w_ = wsv[start+j], t_ = tsv[start+j], d_ = deltas[start+j];
            acc += 2.f*w_*(t_*W - WT) + w_*w_*d_*(1.f/3.f);
            W += w_; WT += w_*t_;
        }
        o_dist[ray] = 0.001f * acc;
    }
}

// ---------------- kP1: per-class block reduce -> cnt, u; block 0 also norm/wsum ----------------
__global__ __launch_bounds__(256) void kP1(
    const float* __restrict__ cntpart, const float* __restrict__ usumpart,
    const float* __restrict__ normpart, const float* __restrict__ wsumpart,
    float* __restrict__ cnt, float* __restrict__ u,
    float* __restrict__ scal, int nblkA)
{
    const int c = blockIdx.x;
    const int t = threadIdx.x;
    const int kk = t & 15;
    const int s  = t >> 4;

    float us = 0.f;
    for (int b = s; b < nblkA; b += 16)
        us += usumpart[(size_t)b*(NC*ND) + c*ND + kk];

    __shared__ float lds[16][17];
    lds[s][kk] = us;

    float cs = (t < nblkA) ? cntpart[t*NC + c] : 0.f;
#pragma unroll
    for (int off = 32; off > 0; off >>= 1) cs += __shfl_xor(cs, off);
    __shared__ float cred[4];
    if ((t & 63) == 0) cred[t >> 6] = cs;
    __syncthreads();

    if (t < 16) {
        const float ctot = cred[0]+cred[1]+cred[2]+cred[3];
        float tot = 0.f;
#pragma unroll
        for (int s2 = 0; s2 < 16; ++s2) tot += lds[s2][t];
        u[c*ND + t] = tot / fmaxf(ctot, 1.f);
        if (t == 0) cnt[c] = ctot;
    }

    if (c == 0) {
        float n = (t < nblkA) ? normpart[t] : 0.f;
        float w2 = (t < nblkA) ? wsumpart[t] : 0.f;
#pragma unroll
        for (int off = 32; off > 0; off >>= 1) {
            n  += __shfl_xor(n, off);
            w2 += __shfl_xor(w2, off);
        }
        __shared__ float nr[4], wr[4];
        if ((t & 63) == 0) { nr[t >> 6] = n; wr[t >> 6] = w2; }
        __syncthreads();
        if (t == 0) {
            scal[0] = nr[0]+nr[1]+nr[2]+nr[3];
            scal[1] = wr[0]+wr[1]+wr[2]+wr[3];
        }
    }
}

// ---------------- kC: per-class deviation partials ----------------
__global__ __launch_bounds__(256) void kC(
    const float* __restrict__ semantic, const int* __restrict__ sam,
    const float* __restrict__ u, float* __restrict__ devpart, int ppb)
{
    __shared__ float u_s[NC*20];
    __shared__ float dev_s[NC];
    const int t = threadIdx.x, b = blockIdx.x;
    for (int j = t; j < NC*ND; j += 256) {
        const int c = j >> 4, k = j & 15;
        u_s[c*20 + k] = u[j];
    }
    for (int j = t; j < NC; j += 256) dev_s[j] = 0.f;
    __syncthreads();
    for (int p = 0; p < ppb; ++p) {
        const int i = (b*ppb + p)*256 + t;
        const int seg = sam[i];
        if (seg > 0) {
            const int cl = seg - 1;
            const float4* sp = (const float4*)(semantic + (size_t)i*ND);
            const float4 a0 = sp[0], a1 = sp[1], a2 = sp[2], a3 = sp[3];
            const float4* up = (const float4*)(u_s + cl*20);
            const float4 u0 = up[0], u1 = up[1], u2 = up[2], u3 = up[3];
            float q, d2 = 0.f;
            q = a0.x-u0.x; d2 += q*q;  q = a0.y-u0.y; d2 += q*q;
            q = a0.z-u0.z; d2 += q*q;  q = a0.w-u0.w; d2 += q*q;
            q = a1.x-u1.x; d2 += q*q;  q = a1.y-u1.y; d2 += q*q;
            q = a1.z-u1.z; d2 += q*q;  q = a1.w-u1.w; d2 += q*q;
            q = a2.x-u2.x; d2 += q*q;  q = a2.y-u2.y; d2 += q*q;
            q = a2.z-u2.z; d2 += q*q;  q = a2.w-u2.w; d2 += q*q;
            q = a3.x-u3.x; d2 += q*q;  q = a3.y-u3.y; d2 += q*q;
            q = a3.z-u3.z; d2 += q*q;  q = a3.w-u3.w; d2 += q*q;
            atomicAdd(&dev_s[cl], sqrtf(d2));
        }
    }
    __syncthreads();
    for (int j = t; j < NC; j += 256) devpart[b*NC + j] = dev_s[j];
}

// ---------------- kP2: per-class phi -> uphi (f32 + bf16 hi), mask; zero scal[2]/done ----------------
__global__ __launch_bounds__(256) void kP2(
    const float* __restrict__ devpart, const float* __restrict__ cnt,
    const float* __restrict__ u, float* __restrict__ uphi,
    unsigned short* __restrict__ uphi_h,
    float* __restrict__ mf, float* __restrict__ scal, int nblkC)
{
    const int c = blockIdx.x;
    const int t = threadIdx.x;

    if (c == 0 && t == 0) {
        scal[2] = 0.f;
        ((unsigned*)scal)[3] = 0u;
    }

    float dv = (t < nblkC) ? devpart[t*NC + c] : 0.f;
#pragma unroll
    for (int off = 32; off > 0; off >>= 1) dv += __shfl_xor(dv, off);
    __shared__ float dred[4];
    __shared__ float inv_s;
    if ((t & 63) == 0) dred[t >> 6] = dv;
    __syncthreads();

    if (t == 0) {
        const float dtot = dred[0]+dred[1]+dred[2]+dred[3];
        const float cs = cnt[c];
        const float csafe = fmaxf(cs, 1.f);
        const float phiraw = dtot / (csafe * logf(cs + 10.f));
        const float phi = fminf(fmaxf(phiraw * 10.f, 0.1f), 1.f);
        inv_s = 1.f / phi;
        mf[c] = (cs > 2.0f) ? 1.f : 0.f;
    }
    __syncthreads();
    if (t < 16) {
        const float v = u[c*ND + t] * inv_s;
        uphi[c*ND + t] = v;
        uphi_h[c*ND + t] = f2bf(v);
    }
}

// ---------------- kD: NCE via MFMA, NO per-thread arrays (rule-20 safe) ----------------
// 512 blocks x 4 waves; wave = 32 pixels (2 A-tiles) x 256 classes.
// A = [sem_hi | sem_lo] (K=32), B = [u_hi | u_hi]: mfma = hi*hi + lo*hi.
// B fragment + mask loaded inside macro-unrolled class loop (literal indices).
__global__ __launch_bounds__(256) void kD(
    const float* __restrict__ semantic, const int* __restrict__ sam,
    const float* __restrict__ uphi, const unsigned short* __restrict__ uphi_h,
    const float* __restrict__ mf,
    float* __restrict__ scal, float* __restrict__ o_sem)
{
    __shared__ float dlds[4][32];
    __shared__ float red_s[4];
    const int t = threadIdx.x;
    const int lane = t & 63;
    const int w = t >> 6;
    const int col = lane & 15;
    const int g   = lane >> 4;
    const int wbase = blockIdx.x * 128 + w * 32;

    short8 A0, A1;
    {
        const float* sp0 = semantic + (size_t)(wbase + col)*ND + (g & 1)*8;
        const float* sp1 = semantic + (size_t)(wbase + 16 + col)*ND + (g & 1)*8;
        const float4 p00 = ((const float4*)sp0)[0], p01 = ((const float4*)sp0)[1];
        const float4 p10 = ((const float4*)sp1)[0], p11 = ((const float4*)sp1)[1];
        float f0[8] = {p00.x,p00.y,p00.z,p00.w,p01.x,p01.y,p01.z,p01.w};
        float f1[8] = {p10.x,p10.y,p10.z,p10.w,p11.x,p11.y,p11.z,p11.w};
        const bool hi = (g < 2);
#pragma unroll
        for (int i = 0; i < 8; ++i) {
            const unsigned short h0 = f2bf(f0[i]);
            const unsigned short h1 = f2bf(f1[i]);
            A0[i] = (short)(hi ? h0 : f2bf(f0[i] - bf2f(h0)));
            A1[i] = (short)(hi ? h1 : f2bf(f1[i] - bf2f(h1)));
        }
    }

    const short8* Bh = (const short8*)uphi_h;
    f32x4 e0 = {0.f,0.f,0.f,0.f}, e1 = {0.f,0.f,0.f,0.f};

#define CT_STEP(ct) { \
        const short8 b = Bh[((ct)*16 + col)*2 + (g & 1)]; \
        const float mm = mf[(ct)*16 + col]; \
        const f32x4 z = {0.f,0.f,0.f,0.f}; \
        const f32x4 d0 = __builtin_amdgcn_mfma_f32_16x16x32_bf16(A0, b, z, 0, 0, 0); \
        const f32x4 d1 = __builtin_amdgcn_mfma_f32_16x16x32_bf16(A1, b, z, 0, 0, 0); \
        e0[0] += mm*__expf(d0[0]); e0[1] += mm*__expf(d0[1]); \
        e0[2] += mm*__expf(d0[2]); e0[3] += mm*__expf(d0[3]); \
        e1[0] += mm*__expf(d1[0]); e1[1] += mm*__expf(d1[1]); \
        e1[2] += mm*__expf(d1[2]); e1[3] += mm*__expf(d1[3]); }

    CT_STEP(0)  CT_STEP(1)  CT_STEP(2)  CT_STEP(3)
    CT_STEP(4)  CT_STEP(5)  CT_STEP(6)  CT_STEP(7)
    CT_STEP(8)  CT_STEP(9)  CT_STEP(10) CT_STEP(11)
    CT_STEP(12) CT_STEP(13) CT_STEP(14) CT_STEP(15)
#undef CT_STEP

    // sum across class-columns (lanes sharing g): xor 1,2,4,8
#pragma unroll
    for (int r = 0; r < 4; ++r) {
        float v0 = e0[r], v1 = e1[r];
        v0 += __shfl_xor(v0, 1); v0 += __shfl_xor(v0, 2);
        v0 += __shfl_xor(v0, 4); v0 += __shfl_xor(v0, 8);
        v1 += __shfl_xor(v1, 1); v1 += __shfl_xor(v1, 2);
        v1 += __shfl_xor(v1, 4); v1 += __shfl_xor(v1, 8);
        if (col == 0) {
            dlds[w][4*g + r]      = v0;   // pixel wbase + 4g + r
            dlds[w][16 + 4*g + r] = v1;   // pixel wbase + 16 + 4g + r
        }
    }
    __syncthreads();

    float contrib = 0.f;
    if (t < 128) {
        const int p = blockIdx.x*128 + t;
        const float denom = dlds[t >> 5][t & 31] + 1e-6f;
        const int seg = sam[p];
        const int cl = (seg > 0) ? (seg - 1) : 0;
        const float4* sp = (const float4*)(semantic + (size_t)p*ND);
        const float4 b0 = sp[0], b1 = sp[1], b2 = sp[2], b3 = sp[3];
        const float4* uo = (const float4*)(uphi + cl*ND);
        const float4 c0 = uo[0], c1 = uo[1], c2 = uo[2], c3 = uo[3];
        const float down =
            b0.x*c0.x + b0.y*c0.y + b0.z*c0.z + b0.w*c0.w +
            b1.x*c1.x + b1.y*c1.y + b1.z*c1.z + b1.w*c1.w +
            b2.x*c2.x + b2.y*c2.y + b2.z*c2.z + b2.w*c2.w +
            b3.x*c3.x + b3.y*c3.y + b3.z*c3.z + b3.w*c3.w;
        const float mo = mf[cl];
        contrib = (seg > 0 && mo > 0.5f) ? (__logf(denom) - down) : 0.f;
    }
#pragma unroll
    for (int off = 32; off > 0; off >>= 1) contrib += __shfl_xor(contrib, off);
    if ((t & 63) == 0) red_s[t >> 6] = contrib;
    __syncthreads();
    if (t == 0) {
        atomicAdd(&scal[2], red_s[0]+red_s[1]+red_s[2]+red_s[3]);
        __threadfence();
        unsigned* done = (unsigned*)(scal + 3);
        const unsigned old = atomicAdd(done, 1u);
        if (old == gridDim.x - 1) {
            const float proto = atomicAdd(&scal[2], 0.f);
            o_sem[0] = 1e-4f * proto + 100.f * scal[0] / fmaxf(scal[1], 1.f);
        }
    }
}

extern "C" void kernel_launch(void* const* d_in, const int* in_sizes, int n_in,
                              void* d_out, int out_size, void* d_ws, size_t ws_size,
                              hipStream_t stream)
{
    const float* rgb_pred = (const float*)d_in[0];
    const float* rgb_gt   = (const float*)d_in[1];
    const float* opacity  = (const float*)d_in[2];
    const float* wsv      = (const float*)d_in[3];
    const float* deltas   = (const float*)d_in[4];
    const float* tsv      = (const float*)d_in[5];
    const int*   rays_a   = (const int*)d_in[6];
    const int*   sam      = (const int*)d_in[7];
    const float* semantic = (const float*)d_in[8];

    float* out    = (float*)d_out;
    float* o_rgb  = out;                 // 196608
    float* o_opac = out + 196608;        // 65536
    float* o_dist = out + 262144;        // 65536
    float* o_sem  = out + 327680;        // 1
    float* wsf    = (float*)d_ws;

    int nblkA = 256, nblkC = 256;
    size_t need = ((size_t)nblkA*NC*(ND+1) + (size_t)nblkC*NC + NC + 2*NC*ND + 2*nblkA + 64) * 4;
    if (ws_size < need) { nblkA = 128; nblkC = 128; }
    const int ppbA = NPIX / (nblkA * 256);
    const int ppbC = NPIX / (nblkC * 256);

    float*          w_cntpart  = wsf;
    float*          w_usum     = w_cntpart + (size_t)nblkA*NC;
    float*          w_devpart  = w_usum + (size_t)nblkA*NC*ND;
    float*          w_cnt      = w_devpart + (size_t)nblkC*NC;
    float*          w_u        = w_cnt + NC;
    float*          w_uphi     = w_u + NC*ND;
    float*          w_scal     = w_uphi + NC*ND;          // [0]=norm [1]=wsum [2]=proto [3]=done
    float*          w_mf       = w_scal + 8;              // NC floats
    float*          w_normpart = w_mf + NC;               // nblkA floats
    float*          w_wsumpart = w_normpart + nblkA;      // nblkA floats
    unsigned short* w_uh       = (unsigned short*)(w_wsumpart + nblkA);  // NC*ND bf16 hi

    kA<<<nblkA, 256, 0, stream>>>(rgb_pred, rgb_gt, opacity, sam, semantic,
                                  o_rgb, o_opac, w_cntpart, w_usum,
                                  w_normpart, w_wsumpart, ppbA);
    kDist<<<NRAYS/RPB, RPB, 0, stream>>>(wsv, deltas, tsv, rays_a, o_dist);
    kP1<<<NC, 256, 0, stream>>>(w_cntpart, w_usum, w_normpart, w_wsumpart,
                                w_cnt, w_u, w_scal, nblkA);
    kC<<<nblkC, 256, 0, stream>>>(semantic, sam, w_u, w_devpart, ppbC);
    kP2<<<NC, 256, 0, stream>>>(w_devpart, w_cnt, w_u, w_uphi, w_uh,
                                w_mf, w_scal, nblkC);
    kD<<<NPIX/128, 256, 0, stream>>>(semantic, sam, w_uphi, w_uh, w_mf, w_scal, o_sem);
}

// Round 15
// 57.607 us; speedup vs baseline: 1.9457x; 1.2249x over previous
//
#include <hip/hip_runtime.h>
#include <hip/hip_bf16.h>

#define NPIX 65536
#define NRAYS 65536
#define SS 48
#define NC 256
#define ND 16
#define RPB 128   // rays per kDist block (128 threads)

typedef __attribute__((ext_vector_type(8))) short short8;
typedef __attribute__((ext_vector_type(4))) float f32x4;

__device__ __forceinline__ unsigned short f2bf(float x) {
    unsigned u = __float_as_uint(x);
    unsigned r = u + 0x7fff + ((u >> 16) & 1);
    return (unsigned short)(r >> 16);
}
__device__ __forceinline__ float bf2f(unsigned short h) {
    return __uint_as_float(((unsigned)h) << 16);
}

// ---------------- kA: pixel pass (rgb, opac, class count/sum, norm partials) ----------------
__global__ __launch_bounds__(256) void kA(
    const float* __restrict__ rgb_pred, const float* __restrict__ rgb_gt,
    const float* __restrict__ opacity, const int* __restrict__ sam,
    const float* __restrict__ semantic,
    float* __restrict__ o_rgb, float* __restrict__ o_opac,
    float* __restrict__ cntpart, float* __restrict__ usumpart,
    float* __restrict__ normpart, float* __restrict__ wsumpart, int ppbA)
{
    __shared__ float cnt_s[NC];
    __shared__ float us_s[NC*17];
    __shared__ float red_s[8];
    const int t = threadIdx.x;
    const int b = blockIdx.x;
    for (int j = t; j < NC; j += 256) cnt_s[j] = 0.f;
    for (int j = t; j < NC*17; j += 256) us_s[j] = 0.f;
    __syncthreads();
    float nloc = 0.f, wloc = 0.f;
    for (int p = 0; p < ppbA; ++p) {
        const int i = (b*ppbA + p)*256 + t;
        const float pr0 = rgb_pred[3*i+0], pr1 = rgb_pred[3*i+1], pr2 = rgb_pred[3*i+2];
        const float g0 = rgb_gt[3*i+0],  g1 = rgb_gt[3*i+1],  g2 = rgb_gt[3*i+2];
        const float d0 = pr0-g0, d1 = pr1-g1, d2 = pr2-g2;
        o_rgb[3*i+0] = d0*d0; o_rgb[3*i+1] = d1*d1; o_rgb[3*i+2] = d2*d2;
        const float o = opacity[i] + 1e-10f;
        o_opac[i] = -0.001f * o * logf(o);
        const float4* sp = (const float4*)(semantic + (size_t)i*ND);
        const float4 a0 = sp[0], a1 = sp[1], a2 = sp[2], a3 = sp[3];
        const int seg = sam[i];
        if (seg > 0) {
            const int cl = seg - 1;
            const float ss =
                a0.x*a0.x + a0.y*a0.y + a0.z*a0.z + a0.w*a0.w +
                a1.x*a1.x + a1.y*a1.y + a1.z*a1.z + a1.w*a1.w +
                a2.x*a2.x + a2.y*a2.y + a2.z*a2.z + a2.w*a2.w +
                a3.x*a3.x + a3.y*a3.y + a3.z*a3.z + a3.w*a3.w;
            const float dn = sqrtf(ss) - 1.f;
            nloc += dn*dn; wloc += 1.f;
            atomicAdd(&cnt_s[cl], 1.f);
            float* up = us_s + cl*17;
            atomicAdd(up+0,  a0.x); atomicAdd(up+1,  a0.y);
            atomicAdd(up+2,  a0.z); atomicAdd(up+3,  a0.w);
            atomicAdd(up+4,  a1.x); atomicAdd(up+5,  a1.y);
            atomicAdd(up+6,  a1.z); atomicAdd(up+7,  a1.w);
            atomicAdd(up+8,  a2.x); atomicAdd(up+9,  a2.y);
            atomicAdd(up+10, a2.z); atomicAdd(up+11, a2.w);
            atomicAdd(up+12, a3.x); atomicAdd(up+13, a3.y);
            atomicAdd(up+14, a3.z); atomicAdd(up+15, a3.w);
        }
    }
    __syncthreads();
    for (int j = t; j < NC; j += 256) cntpart[b*NC + j] = cnt_s[j];
    for (int j = t; j < NC*ND; j += 256) {
        const int c = j >> 4, k = j & 15;
        usumpart[(size_t)b*NC*ND + j] = us_s[c*17 + k];
    }
    for (int off = 32; off > 0; off >>= 1) {
        nloc += __shfl_down(nloc, off);
        wloc += __shfl_down(wloc, off);
    }
    if ((t & 63) == 0) { red_s[t>>6] = nloc; red_s[4 + (t>>6)] = wloc; }
    __syncthreads();
    if (t == 0) {
        normpart[b] = red_s[0]+red_s[1]+red_s[2]+red_s[3];
        wsumpart[b] = red_s[4]+red_s[5]+red_s[6]+red_s[7];
    }
}

// ---------------- kDist: LDS-transposed serial scan, 1 thread/ray ----------------
__global__ __launch_bounds__(128) void kDist(
    const float* __restrict__ wsv, const float* __restrict__ deltas,
    const float* __restrict__ tsv, const int* __restrict__ rays_a,
    float* __restrict__ o_dist)
{
    __shared__ float wS[SS][RPB+1];
    __shared__ float tS[SS][RPB+1];
    __shared__ float dS[SS][RPB+1];
    __shared__ int bad;
    const int t = threadIdx.x;
    const int r0 = blockIdx.x * RPB;
    const int ray = r0 + t;
    if (t == 0) bad = 0;
    __syncthreads();
    const int start = rays_a[3*ray + 1];
    const int cnt   = rays_a[3*ray + 2];
    if (start != ray*SS || cnt != SS) atomicAdd(&bad, 1);
    __syncthreads();

    if (bad == 0) {
        const size_t gb = (size_t)r0 * SS;
        const float4* gw = (const float4*)(wsv + gb);
        const float4* gt = (const float4*)(tsv + gb);
        const float4* gd = (const float4*)(deltas + gb);
        for (int i = t; i < RPB*SS/4; i += 128) {
            const int e = i*4;
            const int rr = e / SS;
            const int jj = e % SS;
            const float4 a = gw[i], b = gt[i], c = gd[i];
            wS[jj+0][rr]=a.x; wS[jj+1][rr]=a.y; wS[jj+2][rr]=a.z; wS[jj+3][rr]=a.w;
            tS[jj+0][rr]=b.x; tS[jj+1][rr]=b.y; tS[jj+2][rr]=b.z; tS[jj+3][rr]=b.w;
            dS[jj+0][rr]=c.x; dS[jj+1][rr]=c.y; dS[jj+2][rr]=c.z; dS[jj+3][rr]=c.w;
        }
        __syncthreads();
        float W = 0.f, WT = 0.f, acc = 0.f;
        for (int j = 0; j < SS; ++j) {
            const float w_ = wS[j][t], t_ = tS[j][t], d_ = dS[j][t];
            acc += 2.f*w_*(t_*W - WT) + w_*w_*d_*(1.f/3.f);
            W += w_; WT += w_*t_;
        }
        o_dist[ray] = 0.001f * acc;
    } else {
        float W = 0.f, WT = 0.f, acc = 0.f;
        for (int j = 0; j < cnt; ++j) {
            const float w_ = wsv[start+j], t_ = tsv[start+j], d_ = deltas[start+j];
            acc += 2.f*w_*(t_*W - WT) + w_*w_*d_*(1.f/3.f);
            W += w_; WT += w_*t_;
        }
        o_dist[ray] = 0.001f * acc;
    }
}

// ---------------- kP1: per-class block reduce -> cnt, u; block 0 also norm/wsum ----------------
__global__ __launch_bounds__(256) void kP1(
    const float* __restrict__ cntpart, const float* __restrict__ usumpart,
    const float* __restrict__ normpart, const float* __restrict__ wsumpart,
    float* __restrict__ cnt, float* __restrict__ u,
    float* __restrict__ scal, int nblkA)
{
    const int c = blockIdx.x;
    const int t = threadIdx.x;
    const int kk = t & 15;
    const int s  = t >> 4;

    float us = 0.f;
    for (int b = s; b < nblkA; b += 16)
        us += usumpart[(size_t)b*(NC*ND) + c*ND + kk];

    __shared__ float lds[16][17];
    lds[s][kk] = us;

    float cs = (t < nblkA) ? cntpart[t*NC + c] : 0.f;
#pragma unroll
    for (int off = 32; off > 0; off >>= 1) cs += __shfl_xor(cs, off);
    __shared__ float cred[4];
    if ((t & 63) == 0) cred[t >> 6] = cs;
    __syncthreads();

    if (t < 16) {
        const float ctot = cred[0]+cred[1]+cred[2]+cred[3];
        float tot = 0.f;
#pragma unroll
        for (int s2 = 0; s2 < 16; ++s2) tot += lds[s2][t];
        u[c*ND + t] = tot / fmaxf(ctot, 1.f);
        if (t == 0) cnt[c] = ctot;
    }

    if (c == 0) {
        float n = (t < nblkA) ? normpart[t] : 0.f;
        float w2 = (t < nblkA) ? wsumpart[t] : 0.f;
#pragma unroll
        for (int off = 32; off > 0; off >>= 1) {
            n  += __shfl_xor(n, off);
            w2 += __shfl_xor(w2, off);
        }
        __shared__ float nr[4], wr[4];
        if ((t & 63) == 0) { nr[t >> 6] = n; wr[t >> 6] = w2; }
        __syncthreads();
        if (t == 0) {
            scal[0] = nr[0]+nr[1]+nr[2]+nr[3];
            scal[1] = wr[0]+wr[1]+wr[2]+wr[3];
        }
    }
}

// ---------------- kC: per-class deviation partials ----------------
__global__ __launch_bounds__(256) void kC(
    const float* __restrict__ semantic, const int* __restrict__ sam,
    const float* __restrict__ u, float* __restrict__ devpart, int ppb)
{
    __shared__ float u_s[NC*20];
    __shared__ float dev_s[NC];
    const int t = threadIdx.x, b = blockIdx.x;
    for (int j = t; j < NC*ND; j += 256) {
        const int c = j >> 4, k = j & 15;
        u_s[c*20 + k] = u[j];
    }
    for (int j = t; j < NC; j += 256) dev_s[j] = 0.f;
    __syncthreads();
    for (int p = 0; p < ppb; ++p) {
        const int i = (b*ppb + p)*256 + t;
        const int seg = sam[i];
        if (seg > 0) {
            const int cl = seg - 1;
            const float4* sp = (const float4*)(semantic + (size_t)i*ND);
            const float4 a0 = sp[0], a1 = sp[1], a2 = sp[2], a3 = sp[3];
            const float4* up = (const float4*)(u_s + cl*20);
            const float4 u0 = up[0], u1 = up[1], u2 = up[2], u3 = up[3];
            float q, d2 = 0.f;
            q = a0.x-u0.x; d2 += q*q;  q = a0.y-u0.y; d2 += q*q;
            q = a0.z-u0.z; d2 += q*q;  q = a0.w-u0.w; d2 += q*q;
            q = a1.x-u1.x; d2 += q*q;  q = a1.y-u1.y; d2 += q*q;
            q = a1.z-u1.z; d2 += q*q;  q = a1.w-u1.w; d2 += q*q;
            q = a2.x-u2.x; d2 += q*q;  q = a2.y-u2.y; d2 += q*q;
            q = a2.z-u2.z; d2 += q*q;  q = a2.w-u2.w; d2 += q*q;
            q = a3.x-u3.x; d2 += q*q;  q = a3.y-u3.y; d2 += q*q;
            q = a3.z-u3.z; d2 += q*q;  q = a3.w-u3.w; d2 += q*q;
            atomicAdd(&dev_s[cl], sqrtf(d2));
        }
    }
    __syncthreads();
    for (int j = t; j < NC; j += 256) devpart[b*NC + j] = dev_s[j];
}

// ---------------- kP2: per-class phi -> uphi (f32 + bf16 hi), mask; zero scal[2]/done ----------------
__global__ __launch_bounds__(256) void kP2(
    const float* __restrict__ devpart, const float* __restrict__ cnt,
    const float* __restrict__ u, float* __restrict__ uphi,
    unsigned short* __restrict__ uphi_h,
    float* __restrict__ mf, float* __restrict__ scal, int nblkC)
{
    const int c = blockIdx.x;
    const int t = threadIdx.x;

    if (c == 0 && t == 0) {
        scal[2] = 0.f;
        ((unsigned*)scal)[3] = 0u;
    }

    float dv = (t < nblkC) ? devpart[t*NC + c] : 0.f;
#pragma unroll
    for (int off = 32; off > 0; off >>= 1) dv += __shfl_xor(dv, off);
    __shared__ float dred[4];
    __shared__ float inv_s;
    if ((t & 63) == 0) dred[t >> 6] = dv;
    __syncthreads();

    if (t == 0) {
        const float dtot = dred[0]+dred[1]+dred[2]+dred[3];
        const float cs = cnt[c];
        const float csafe = fmaxf(cs, 1.f);
        const float phiraw = dtot / (csafe * logf(cs + 10.f));
        const float phi = fminf(fmaxf(phiraw * 10.f, 0.1f), 1.f);
        inv_s = 1.f / phi;
        mf[c] = (cs > 2.0f) ? 1.f : 0.f;
    }
    __syncthreads();
    if (t < 16) {
        const float v = u[c*ND + t] * inv_s;
        uphi[c*ND + t] = v;
        uphi_h[c*ND + t] = f2bf(v);
    }
}

// ---------------- kD: NCE via MFMA, LDS-staged B, no per-thread arrays ----------------
// 512 blocks x 4 waves; wave = 32 pixels (2 A-tiles) x 256 classes.
// A = [sem_hi | sem_lo] (K=32), B = [u_hi | u_hi]: mfma = hi*hi + lo*hi.
// uphi_h (8 KB) + mf (1 KB) staged to LDS once; macro loop reads LDS only.
__global__ __launch_bounds__(256, 2) void kD(
    const float* __restrict__ semantic, const int* __restrict__ sam,
    const float* __restrict__ uphi, const unsigned short* __restrict__ uphi_h,
    const float* __restrict__ mf,
    float* __restrict__ scal, float* __restrict__ o_sem)
{
    __shared__ short8 Bs[NC*2];        // 8 KB
    __shared__ float mfs[NC];          // 1 KB
    __shared__ float dlds[4][32];
    __shared__ float red_s[4];
    const int t = threadIdx.x;
    const int lane = t & 63;
    const int w = t >> 6;
    const int col = lane & 15;
    const int g   = lane >> 4;
    const int wbase = blockIdx.x * 128 + w * 32;

    {   // stage B (512 short8) + mf (256 f32)
        const short8* Bg = (const short8*)uphi_h;
        Bs[t]       = Bg[t];
        Bs[256 + t] = Bg[256 + t];
        mfs[t] = mf[t];
    }

    short8 A0, A1;
    {
        const float* sp0 = semantic + (size_t)(wbase + col)*ND + (g & 1)*8;
        const float* sp1 = semantic + (size_t)(wbase + 16 + col)*ND + (g & 1)*8;
        const float4 p00 = ((const float4*)sp0)[0], p01 = ((const float4*)sp0)[1];
        const float4 p10 = ((const float4*)sp1)[0], p11 = ((const float4*)sp1)[1];
        float f0[8] = {p00.x,p00.y,p00.z,p00.w,p01.x,p01.y,p01.z,p01.w};
        float f1[8] = {p10.x,p10.y,p10.z,p10.w,p11.x,p11.y,p11.z,p11.w};
        const bool hi = (g < 2);
#pragma unroll
        for (int i = 0; i < 8; ++i) {
            const unsigned short h0 = f2bf(f0[i]);
            const unsigned short h1 = f2bf(f1[i]);
            A0[i] = (short)(hi ? h0 : f2bf(f0[i] - bf2f(h0)));
            A1[i] = (short)(hi ? h1 : f2bf(f1[i] - bf2f(h1)));
        }
    }
    __syncthreads();

    f32x4 e0 = {0.f,0.f,0.f,0.f}, e1 = {0.f,0.f,0.f,0.f};

#define CT_STEP(ct) { \
        const short8 b = Bs[(ct)*32 + col*2 + (g & 1)]; \
        const float mm = mfs[(ct)*16 + col]; \
        const f32x4 z = {0.f,0.f,0.f,0.f}; \
        const f32x4 d0 = __builtin_amdgcn_mfma_f32_16x16x32_bf16(A0, b, z, 0, 0, 0); \
        const f32x4 d1 = __builtin_amdgcn_mfma_f32_16x16x32_bf16(A1, b, z, 0, 0, 0); \
        e0[0] += mm*__expf(d0[0]); e0[1] += mm*__expf(d0[1]); \
        e0[2] += mm*__expf(d0[2]); e0[3] += mm*__expf(d0[3]); \
        e1[0] += mm*__expf(d1[0]); e1[1] += mm*__expf(d1[1]); \
        e1[2] += mm*__expf(d1[2]); e1[3] += mm*__expf(d1[3]); }

    CT_STEP(0)  CT_STEP(1)  CT_STEP(2)  CT_STEP(3)
    CT_STEP(4)  CT_STEP(5)  CT_STEP(6)  CT_STEP(7)
    CT_STEP(8)  CT_STEP(9)  CT_STEP(10) CT_STEP(11)
    CT_STEP(12) CT_STEP(13) CT_STEP(14) CT_STEP(15)
#undef CT_STEP

    // sum across class-columns (lanes sharing g): xor 1,2,4,8
#pragma unroll
    for (int r = 0; r < 4; ++r) {
        float v0 = e0[r], v1 = e1[r];
        v0 += __shfl_xor(v0, 1); v0 += __shfl_xor(v0, 2);
        v0 += __shfl_xor(v0, 4); v0 += __shfl_xor(v0, 8);
        v1 += __shfl_xor(v1, 1); v1 += __shfl_xor(v1, 2);
        v1 += __shfl_xor(v1, 4); v1 += __shfl_xor(v1, 8);
        if (col == 0) {
            dlds[w][4*g + r]      = v0;   // pixel wbase + 4g + r
            dlds[w][16 + 4*g + r] = v1;   // pixel wbase + 16 + 4g + r
        }
    }
    __syncthreads();

    float contrib = 0.f;
    if (t < 128) {
        const int p = blockIdx.x*128 + t;
        const float denom = dlds[t >> 5][t & 31] + 1e-6f;
        const int seg = sam[p];
        const int cl = (seg > 0) ? (seg - 1) : 0;
        const float4* sp = (const float4*)(semantic + (size_t)p*ND);
        const float4 b0 = sp[0], b1 = sp[1], b2 = sp[2], b3 = sp[3];
        const float4* uo = (const float4*)(uphi + cl*ND);
        const float4 c0 = uo[0], c1 = uo[1], c2 = uo[2], c3 = uo[3];
        const float down =
            b0.x*c0.x + b0.y*c0.y + b0.z*c0.z + b0.w*c0.w +
            b1.x*c1.x + b1.y*c1.y + b1.z*c1.z + b1.w*c1.w +
            b2.x*c2.x + b2.y*c2.y + b2.z*c2.z + b2.w*c2.w +
            b3.x*c3.x + b3.y*c3.y + b3.z*c3.z + b3.w*c3.w;
        const float mo = mfs[cl];
        contrib = (seg > 0 && mo > 0.5f) ? (__logf(denom) - down) : 0.f;
    }
#pragma unroll
    for (int off = 32; off > 0; off >>= 1) contrib += __shfl_xor(contrib, off);
    if ((t & 63) == 0) red_s[t >> 6] = contrib;
    __syncthreads();
    if (t == 0) {
        atomicAdd(&scal[2], red_s[0]+red_s[1]+red_s[2]+red_s[3]);
        __threadfence();
        unsigned* done = (unsigned*)(scal + 3);
        const unsigned old = atomicAdd(done, 1u);
        if (old == gridDim.x - 1) {
            const float proto = atomicAdd(&scal[2], 0.f);
            o_sem[0] = 1e-4f * proto + 100.f * scal[0] / fmaxf(scal[1], 1.f);
        }
    }
}

extern "C" void kernel_launch(void* const* d_in, const int* in_sizes, int n_in,
                              void* d_out, int out_size, void* d_ws, size_t ws_size,
                              hipStream_t stream)
{
    const float* rgb_pred = (const float*)d_in[0];
    const float* rgb_gt   = (const float*)d_in[1];
    const float* opacity  = (const float*)d_in[2];
    const float* wsv      = (const float*)d_in[3];
    const float* deltas   = (const float*)d_in[4];
    const float* tsv      = (const float*)d_in[5];
    const int*   rays_a   = (const int*)d_in[6];
    const int*   sam      = (const int*)d_in[7];
    const float* semantic = (const float*)d_in[8];

    float* out    = (float*)d_out;
    float* o_rgb  = out;                 // 196608
    float* o_opac = out + 196608;        // 65536
    float* o_dist = out + 262144;        // 65536
    float* o_sem  = out + 327680;        // 1
    float* wsf    = (float*)d_ws;

    int nblkA = 256, nblkC = 256;
    size_t need = ((size_t)nblkA*NC*(ND+1) + (size_t)nblkC*NC + NC + 2*NC*ND + 2*nblkA + 64) * 4;
    if (ws_size < need) { nblkA = 128; nblkC = 128; }
    const int ppbA = NPIX / (nblkA * 256);
    const int ppbC = NPIX / (nblkC * 256);

    float*          w_cntpart  = wsf;
    float*          w_usum     = w_cntpart + (size_t)nblkA*NC;
    float*          w_devpart  = w_usum + (size_t)nblkA*NC*ND;
    float*          w_cnt      = w_devpart + (size_t)nblkC*NC;
    float*          w_u        = w_cnt + NC;
    float*          w_uphi     = w_u + NC*ND;
    float*          w_scal     = w_uphi + NC*ND;          // [0]=norm [1]=wsum [2]=proto [3]=done
    float*          w_mf       = w_scal + 8;              // NC floats
    float*          w_normpart = w_mf + NC;               // nblkA floats
    float*          w_wsumpart = w_normpart + nblkA;      // nblkA floats
    unsigned short* w_uh       = (unsigned short*)(w_wsumpart + nblkA);  // NC*ND bf16 hi

    kA<<<nblkA, 256, 0, stream>>>(rgb_pred, rgb_gt, opacity, sam, semantic,
                                  o_rgb, o_opac, w_cntpart, w_usum,
                                  w_normpart, w_wsumpart, ppbA);
    kDist<<<NRAYS/RPB, RPB, 0, stream>>>(wsv, deltas, tsv, rays_a, o_dist);
    kP1<<<NC, 256, 0, stream>>>(w_cntpart, w_usum, w_normpart, w_wsumpart,
                                w_cnt, w_u, w_scal, nblkA);
    kC<<<nblkC, 256, 0, stream>>>(semantic, sam, w_u, w_devpart, ppbC);
    kP2<<<NC, 256, 0, stream>>>(w_devpart, w_cnt, w_u, w_uphi, w_uh,
                                w_mf, w_scal, nblkC);
    kD<<<NPIX/128, 256, 0, stream>>>(semantic, sam, w_uphi, w_uh, w_mf, w_scal, o_sem);
}